// Round 12
// baseline (653.726 us; speedup 1.0000x reference)
//
#include <hip/hip_runtime.h>
#include <hip/hip_fp16.h>
#include <math.h>

// Volume dims (1,1,160,192,160) fp32
#define DD 160
#define HHH 192
#define WWW 160
constexpr int HW = HHH * WWW;          // 30720
constexpr int NV = DD * HHH * WWW;     // 4915200
constexpr int W4 = WWW / 4;            // 40
constexpr int HC = 4;                  // whsum H-chunk (measured best)
constexpr int DC = 4;                  // dcc D-chunk (4-wide): 160/4 = 40 chunks -> 1200 blocks
constexpr int SC = 5;                  // sobel D-chunk

constexpr int NB_WH  = (W4 * DD * (HHH / HC)) / 256;   // 1200
constexpr int NB_SO  = (W4 * HHH * (DD / SC)) / 256;   // 960
constexpr int NB_LAP = (NV / 4) / 256;                 // 4800
constexpr int NB_DCC = (W4 * HHH * (DD / DC)) / 256;   // 1200

__device__ __forceinline__ float4 ldg4(const float* __restrict__ p, int idx, bool ok) {
    float4 z = make_float4(0.f, 0.f, 0.f, 0.f);
    return ok ? *(const float4*)(p + idx) : z;
}

__device__ __forceinline__ void st_h4(__half* __restrict__ t, int idx,
                                      float s0, float s1, float s2, float s3) {
    union { __half2 h2[2]; uint2 u; } pk;
    pk.h2[0] = __floats2half2_rn(s0, s1);
    pk.h2[1] = __floats2half2_rn(s2, s3);
    *(uint2*)(t + idx) = pk.u;  // idx%4==0 -> 8B aligned
}

__device__ __forceinline__ void ld_h4(const __half* __restrict__ t, int idx, float o[4]) {
    union { __half2 h2[2]; uint2 u; } pk;
    pk.u = *(const uint2*)(t + idx);
    o[0] = __low2float(pk.h2[0]); o[1] = __high2float(pk.h2[0]);
    o[2] = __low2float(pk.h2[1]); o[3] = __high2float(pk.h2[1]);
}

// ---- Laplacian body, 4 outputs/thread, fp16 out ----------------------------
__device__ __forceinline__ void lap_body(int t, const float* __restrict__ a,
                                         const float* __restrict__ b,
                                         __half* __restrict__ oa, __half* __restrict__ ob) {
    int w = (t % W4) * 4;
    int h = (t / W4) % HHH;
    int d = t / (W4 * HHH);
    int idx = (d * HHH + h) * WWW + w;
    bool dok0 = d > 0, dok1 = d < DD - 1, hok0 = h > 0, hok1 = h < HHH - 1;
#pragma unroll
    for (int s = 0; s < 2; s++) {
        const float* p = s ? b : a;
        __half* o = s ? ob : oa;
        float4 c = *(const float4*)(p + idx);
        float m1 = (w > 0) ? p[idx - 1] : 0.f;
        float p4 = (w + 4 < WWW) ? p[idx + 4] : 0.f;
        float4 dm = ldg4(p, idx - HW, dok0);
        float4 dp = ldg4(p, idx + HW, dok1);
        float4 hm = ldg4(p, idx - WWW, hok0);
        float4 hp = ldg4(p, idx + WWW, hok1);
        st_h4(o, idx,
              6.f * c.x - (m1 + c.y + dm.x + dp.x + hm.x + hp.x),
              6.f * c.y - (c.x + c.z + dm.y + dp.y + hm.y + hp.y),
              6.f * c.z - (c.y + c.w + dm.z + dp.z + hm.z + hp.z),
              6.f * c.w - (c.z + p4 + dm.w + dp.w + hm.w + hp.w));
    }
}

// ---- Sobel body, d-marching ring, 4 outputs/thread, fp16 out ---------------
__device__ __forceinline__ void sobel_slice(const float* __restrict__ p, int s, int h, int w,
                                            float a1[4], float a2[4], float a3[4]) {
#pragma unroll
    for (int k = 0; k < 4; k++) { a1[k] = 0.f; a2[k] = 0.f; a3[k] = 0.f; }
#pragma unroll
    for (int kh = -1; kh <= 1; kh++) {
        int h2 = h + kh;
        if ((unsigned)h2 < (unsigned)HHH) {
            int rb = (s * HHH + h2) * WWW + w;
            float4 cen = *(const float4*)(p + rb);
            float xm = (w > 0) ? p[rb - 1] : 0.f;
            float xp = (w + 4 < WWW) ? p[rb + 4] : 0.f;
            float xv[6] = {xm, cen.x, cen.y, cen.z, cen.w, xp};
            float smh = (kh == 0) ? 2.f : 1.f;
            float grh = (float)kh;
#pragma unroll
            for (int k = 0; k < 4; k++) {
                float gw = xv[k + 2] - xv[k];
                float pw = xv[k] + xv[k + 1] + xv[k + 2];
                float sw = pw + xv[k + 1];
                a1[k] += smh * gw;
                a2[k] += sw;
                a3[k] += grh * pw;
            }
        }
    }
}

__device__ __forceinline__ void sobel_body(int t, const float* __restrict__ a,
                                           const float* __restrict__ b,
                                           __half* __restrict__ oa, __half* __restrict__ ob) {
    int w = (t % W4) * 4;
    int h = (t / W4) % HHH;
    int c = t / (W4 * HHH);
    int d0 = c * SC;

    float A1[2][3][4], A2[2][3][4], A3[2][3][4];
#pragma unroll
    for (int r = 0; r < 2; r++)
#pragma unroll
        for (int j = 0; j < 3; j++)
#pragma unroll
            for (int k = 0; k < 4; k++) { A1[r][j][k] = 0.f; A2[r][j][k] = 0.f; A3[r][j][k] = 0.f; }

#pragma unroll
    for (int i = 0; i < SC + 2; i++) {
        int s = d0 - 1 + i;
#pragma unroll
        for (int r = 0; r < 2; r++)
#pragma unroll
            for (int k = 0; k < 4; k++) {
                A1[r][0][k] = A1[r][1][k]; A2[r][0][k] = A2[r][1][k]; A3[r][0][k] = A3[r][1][k];
                A1[r][1][k] = A1[r][2][k]; A2[r][1][k] = A2[r][2][k]; A3[r][1][k] = A3[r][2][k];
            }
        if (s >= 0 && s < DD) {
            sobel_slice(a, s, h, w, A1[0][2], A2[0][2], A3[0][2]);
            sobel_slice(b, s, h, w, A1[1][2], A2[1][2], A3[1][2]);
        } else {
#pragma unroll
            for (int r = 0; r < 2; r++)
#pragma unroll
                for (int k = 0; k < 4; k++) { A1[r][2][k] = 0.f; A2[r][2][k] = 0.f; A3[r][2][k] = 0.f; }
        }
        if (i >= 2) {
            int d = s - 1;
            int idx = (d * HHH + h) * WWW + w;
            float va[4], vb[4];
#pragma unroll
            for (int k = 0; k < 4; k++) {
                float gx = A1[0][0][k] + A1[0][1][k] + A1[0][2][k];
                float gy = A2[0][2][k] - A2[0][0][k];
                float gz = A3[0][0][k] + 2.f * A3[0][1][k] + A3[0][2][k];
                va[k] = sqrtf(gx * gx + gy * gy + gz * gz);
                gx = A1[1][0][k] + A1[1][1][k] + A1[1][2][k];
                gy = A2[1][2][k] - A2[1][0][k];
                gz = A3[1][0][k] + 2.f * A3[1][1][k] + A3[1][2][k];
                vb[k] = sqrtf(gx * gx + gy * gy + gz * gz);
            }
            st_h4(oa, idx, va[0], va[1], va[2], va[3]);
            st_h4(ob, idx, vb[0], vb[1], vb[2], vb[3]);
        }
    }
}

// ---- W+H box sums of 5 moments, guarded 12-tap row loads -------------------
__device__ __forceinline__ void q5_from(const float x[12], const float y[12], float q[5][4]) {
    float s0 = 0, s1 = 0, s2 = 0, s3 = 0, s4 = 0;
#pragma unroll
    for (int j = 0; j < 9; j++) {
        s0 += x[j]; s1 += y[j];
        s2 += x[j] * x[j]; s3 += y[j] * y[j]; s4 += x[j] * y[j];
    }
    q[0][0] = s0; q[1][0] = s1; q[2][0] = s2; q[3][0] = s3; q[4][0] = s4;
#pragma unroll
    for (int k = 1; k < 4; k++) {
        q[0][k] = q[0][k - 1] + x[k + 8] - x[k - 1];
        q[1][k] = q[1][k - 1] + y[k + 8] - y[k - 1];
        q[2][k] = q[2][k - 1] + x[k + 8] * x[k + 8] - x[k - 1] * x[k - 1];
        q[3][k] = q[3][k - 1] + y[k + 8] * y[k + 8] - y[k - 1] * y[k - 1];
        q[4][k] = q[4][k - 1] + x[k + 8] * y[k + 8] - x[k - 1] * y[k - 1];
    }
}

__device__ __forceinline__ void ld12g(const float* __restrict__ p, int rowbase, int w, bool ok,
                                      float x[12]) {
    bool lo = ok && (w >= 4);
    bool hi = ok && (w + 7 < WWW);
    float4 x0 = ldg4(p, rowbase + w - 4, lo);
    float4 x1 = ldg4(p, rowbase + w, ok);
    float4 x2 = ldg4(p, rowbase + w + 4, hi);
    x[0] = x0.x; x[1] = x0.y; x[2] = x0.z; x[3] = x0.w;
    x[4] = x1.x; x[5] = x1.y; x[6] = x1.z; x[7] = x1.w;
    x[8] = x2.x; x[9] = x2.y; x[10] = x2.z; x[11] = x2.w;
}

__device__ __forceinline__ void ld12g(const __half* __restrict__ p, int rowbase, int w, bool ok,
                                      float x[12]) {
    bool lo = ok && (w >= 4);
    bool hi = ok && (w + 7 < WWW);
    union { __half2 h2[2]; uint2 u; } u0, u1, u2;
    uint2 z = make_uint2(0, 0);
    u0.u = lo ? *(const uint2*)(p + rowbase + w - 4) : z;
    u1.u = ok ? *(const uint2*)(p + rowbase + w) : z;
    u2.u = hi ? *(const uint2*)(p + rowbase + w + 4) : z;
    x[0] = __low2float(u0.h2[0]); x[1] = __high2float(u0.h2[0]);
    x[2] = __low2float(u0.h2[1]); x[3] = __high2float(u0.h2[1]);
    x[4] = __low2float(u1.h2[0]); x[5] = __high2float(u1.h2[0]);
    x[6] = __low2float(u1.h2[1]); x[7] = __high2float(u1.h2[1]);
    x[8] = __low2float(u2.h2[0]); x[9] = __high2float(u2.h2[0]);
    x[10] = __low2float(u2.h2[1]); x[11] = __high2float(u2.h2[1]);
}

template <typename T>
__device__ void whsum_body(int t, const T* __restrict__ a, const T* __restrict__ b,
                           __half* __restrict__ t0, __half* __restrict__ t1,
                           __half* __restrict__ t2, __half* __restrict__ t3,
                           __half* __restrict__ t4) {
    int w = (t % W4) * 4;
    int d = (t / W4) % DD;
    int c = t / (W4 * DD);
    int h0 = c * HC;

    float S[5][4] = {{0}};
    for (int j = 0; j < 9; j++) {
        int r = h0 - 4 + j;
        bool ok = (unsigned)r < (unsigned)HHH;
        float x[12], y[12], q[5][4];
        ld12g(a, (d * HHH + r) * WWW, w, ok, x);
        ld12g(b, (d * HHH + r) * WWW, w, ok, y);
        q5_from(x, y, q);
#pragma unroll
        for (int qq = 0; qq < 5; qq++)
#pragma unroll
            for (int k = 0; k < 4; k++) S[qq][k] += q[qq][k];
    }
    {
        int idx = (d * HHH + h0) * WWW + w;
        st_h4(t0, idx, S[0][0], S[0][1], S[0][2], S[0][3]);
        st_h4(t1, idx, S[1][0], S[1][1], S[1][2], S[1][3]);
        st_h4(t2, idx, S[2][0], S[2][1], S[2][2], S[2][3]);
        st_h4(t3, idx, S[3][0], S[3][1], S[3][2], S[3][3]);
        st_h4(t4, idx, S[4][0], S[4][1], S[4][2], S[4][3]);
    }
#pragma unroll
    for (int h = h0 + 1; h < h0 + HC; h++) {
        int rin = h + 4, rout = h - 5;
        bool oki = rin < HHH, oko = rout >= 0;
        // batch all 24 tap-loads (12 per row) before any compute — needs the
        // 128-VGPR budget from __launch_bounds__(256,4); at the default 64-cap
        // this spills (R5: +250 MB scratch traffic).
        float xi[12], yi[12], xo[12], yo[12];
        ld12g(a, (d * HHH + rin) * WWW, w, oki, xi);
        ld12g(b, (d * HHH + rin) * WWW, w, oki, yi);
        ld12g(a, (d * HHH + rout) * WWW, w, oko, xo);
        ld12g(b, (d * HHH + rout) * WWW, w, oko, yo);
        float qi[5][4], qo[5][4];
        q5_from(xi, yi, qi);
        q5_from(xo, yo, qo);
#pragma unroll
        for (int qq = 0; qq < 5; qq++)
#pragma unroll
            for (int k = 0; k < 4; k++) S[qq][k] += qi[qq][k] - qo[qq][k];
        int idx = (d * HHH + h) * WWW + w;
        st_h4(t0, idx, S[0][0], S[0][1], S[0][2], S[0][3]);
        st_h4(t1, idx, S[1][0], S[1][1], S[1][2], S[1][3]);
        st_h4(t2, idx, S[2][0], S[2][1], S[2][2], S[2][3]);
        st_h4(t3, idx, S[3][0], S[3][1], S[3][2], S[3][3]);
        st_h4(t4, idx, S[4][0], S[4][1], S[4][2], S[4][3]);
    }
}

// ---- D box-sum + cc + reduction, 4-wide fp16 loads, sliding D window --------
__device__ __forceinline__ float cc1(float s0, float s1, float s2, float s3, float s4) {
    const float wsz = 729.0f;
    const float inv = 1.0f / 729.0f;
    float uI = s0 * inv;
    float uJ = s1 * inv;
    float cross = s4 - uJ * s0 - uI * s1 + uI * uJ * wsz;
    float Iv = s2 - 2.0f * uI * s0 + uI * uI * wsz;
    float Jv = s3 - 2.0f * uJ * s1 + uJ * uJ * wsz;
    return cross * cross / (Iv * Jv + 1e-5f);
}

__device__ void dcc_body(int t, const __half* __restrict__ t0, const __half* __restrict__ t1,
                         const __half* __restrict__ t2, const __half* __restrict__ t3,
                         const __half* __restrict__ t4, double* __restrict__ acc, int pair) {
    int w = (t % W4) * 4;
    int h = (t / W4) % HHH;
    int c = t / (W4 * HHH);
    int d0 = c * DC;

    float S[5][4] = {{0}};
    for (int j = 0; j < 9; j++) {
        int r = d0 - 4 + j;
        if ((unsigned)r < (unsigned)DD) {
            int idx = (r * HHH + h) * WWW + w;
            float v[5][4];
            ld_h4(t0, idx, v[0]); ld_h4(t1, idx, v[1]); ld_h4(t2, idx, v[2]);
            ld_h4(t3, idx, v[3]); ld_h4(t4, idx, v[4]);
#pragma unroll
            for (int q = 0; q < 5; q++)
#pragma unroll
                for (int k = 0; k < 4; k++) S[q][k] += v[q][k];
        }
    }
    float local = 0.f;
#pragma unroll
    for (int k = 0; k < 4; k++) local += cc1(S[0][k], S[1][k], S[2][k], S[3][k], S[4][k]);
#pragma unroll
    for (int d = 1; d < DC; d++) {
        int rin = d0 + d + 4, rout = d0 + d - 5;
        bool oki = rin < DD, oko = rout >= 0;
        int iin = ((oki ? rin : 0) * HHH + h) * WWW + w;
        int iout = ((oko ? rout : 0) * HHH + h) * WWW + w;
        // batch vin+vout loads (10) before updating S
        float vin[5][4], vout[5][4];
        if (oki) {
            ld_h4(t0, iin, vin[0]); ld_h4(t1, iin, vin[1]); ld_h4(t2, iin, vin[2]);
            ld_h4(t3, iin, vin[3]); ld_h4(t4, iin, vin[4]);
        } else {
#pragma unroll
            for (int q = 0; q < 5; q++)
#pragma unroll
                for (int k = 0; k < 4; k++) vin[q][k] = 0.f;
        }
        if (oko) {
            ld_h4(t0, iout, vout[0]); ld_h4(t1, iout, vout[1]); ld_h4(t2, iout, vout[2]);
            ld_h4(t3, iout, vout[3]); ld_h4(t4, iout, vout[4]);
        } else {
#pragma unroll
            for (int q = 0; q < 5; q++)
#pragma unroll
                for (int k = 0; k < 4; k++) vout[q][k] = 0.f;
        }
#pragma unroll
        for (int q = 0; q < 5; q++)
#pragma unroll
            for (int k = 0; k < 4; k++) S[q][k] += vin[q][k] - vout[q][k];
#pragma unroll
        for (int k = 0; k < 4; k++) local += cc1(S[0][k], S[1][k], S[2][k], S[3][k], S[4][k]);
    }

    for (int off = 32; off > 0; off >>= 1) local += __shfl_down(local, off);
    __shared__ float wsum_[4];
    if ((threadIdx.x & 63) == 0) wsum_[threadIdx.x >> 6] = local;
    __syncthreads();
    if (threadIdx.x == 0) {
        float s = wsum_[0] + wsum_[1] + wsum_[2] + wsum_[3];
        atomicAdd(&acc[pair], (double)s);
    }
}

// ---- Stage kernels ----------------------------------------------------------
// S1: LJF order (whsum, sobel, lap) + zero block.
__global__ void __launch_bounds__(256, 4)
stage1(const float* __restrict__ yt, const float* __restrict__ yp,
       __half* __restrict__ e1a, __half* __restrict__ e1b,
       __half* __restrict__ e2a, __half* __restrict__ e2b,
       __half* __restrict__ ta0, __half* __restrict__ ta1,
       __half* __restrict__ ta2, __half* __restrict__ ta3,
       __half* __restrict__ ta4, double* __restrict__ acc) {
    int b = blockIdx.x;
    if (b < NB_WH) {
        whsum_body<float>(b * 256 + threadIdx.x, yt, yp, ta0, ta1, ta2, ta3, ta4);
    } else if (b < NB_WH + NB_SO) {
        sobel_body((b - NB_WH) * 256 + threadIdx.x, yt, yp, e2a, e2b);
    } else if (b < NB_WH + NB_SO + NB_LAP) {
        lap_body((b - NB_WH - NB_SO) * 256 + threadIdx.x, yt, yp, e1a, e1b);
    } else {
        if (threadIdx.x < 3) acc[threadIdx.x] = 0.0;
    }
}

// S2/S3: whsum first, then dcc.
__global__ void __launch_bounds__(256, 4)
stage23(const __half* __restrict__ ea, const __half* __restrict__ eb,
        __half* __restrict__ o0, __half* __restrict__ o1,
        __half* __restrict__ o2, __half* __restrict__ o3,
        __half* __restrict__ o4,
        const __half* __restrict__ i0, const __half* __restrict__ i1,
        const __half* __restrict__ i2, const __half* __restrict__ i3,
        const __half* __restrict__ i4, double* __restrict__ acc, int pair) {
    int b = blockIdx.x;
    if (b < NB_WH) {
        whsum_body<__half>(b * 256 + threadIdx.x, ea, eb, o0, o1, o2, o3, o4);
    } else {
        dcc_body((b - NB_WH) * 256 + threadIdx.x, i0, i1, i2, i3, i4, acc, pair);
    }
}

__global__ void __launch_bounds__(256, 4)
dcc_k(const __half* __restrict__ t0, const __half* __restrict__ t1,
      const __half* __restrict__ t2, const __half* __restrict__ t3,
      const __half* __restrict__ t4, double* __restrict__ acc, int pair) {
    dcc_body(blockIdx.x * 256 + threadIdx.x, t0, t1, t2, t3, t4, acc, pair);
}

__global__ void finalize_k(const double* __restrict__ acc, float* __restrict__ out) {
    if (threadIdx.x == 0) {
        double v = 0.8 * acc[0] + 0.1 * acc[1] + 0.1 * acc[2];
        out[0] = (float)(-v / (double)NV);
    }
}

extern "C" void kernel_launch(void* const* d_in, const int* in_sizes, int n_in,
                              void* d_out, int out_size, void* d_ws, size_t ws_size,
                              hipStream_t stream) {
    const float* yt = (const float*)d_in[0];
    const float* yp = (const float*)d_in[1];
    float* out = (float*)d_out;

    // ws layout (halves after 256B acc header), 14*NV halves = 137.6 MB:
    // e1a e1b e2a e2b | tA (5 vols) | tB (5 vols)
    double* acc = (double*)d_ws;
    __half* base = (__half*)((char*)d_ws + 256);
    __half* e1a = base + 0 * (size_t)NV;
    __half* e1b = base + 1 * (size_t)NV;
    __half* e2a = base + 2 * (size_t)NV;
    __half* e2b = base + 3 * (size_t)NV;
    __half* tA = base + 4 * (size_t)NV;   // 5 vols
    __half* tB = base + 9 * (size_t)NV;   // 5 vols

    dim3 blk(256);

    // S1: whsum_p0 + sobel + lap + zero (LJF order)
    hipLaunchKernelGGL(stage1, dim3(NB_WH + NB_SO + NB_LAP + 1), blk, 0, stream,
                       yt, yp, e1a, e1b, e2a, e2b,
                       tA, tA + NV, tA + 2 * (size_t)NV, tA + 3 * (size_t)NV, tA + 4 * (size_t)NV,
                       acc);
    // S2: whsum_p1(lap->tB) + dcc_p0(tA)
    hipLaunchKernelGGL(stage23, dim3(NB_WH + NB_DCC), blk, 0, stream,
                       e1a, e1b,
                       tB, tB + NV, tB + 2 * (size_t)NV, tB + 3 * (size_t)NV, tB + 4 * (size_t)NV,
                       tA, tA + NV, tA + 2 * (size_t)NV, tA + 3 * (size_t)NV, tA + 4 * (size_t)NV,
                       acc, 0);
    // S3: whsum_p2(sobel->tA) + dcc_p1(tB)
    hipLaunchKernelGGL(stage23, dim3(NB_WH + NB_DCC), blk, 0, stream,
                       e2a, e2b,
                       tA, tA + NV, tA + 2 * (size_t)NV, tA + 3 * (size_t)NV, tA + 4 * (size_t)NV,
                       tB, tB + NV, tB + 2 * (size_t)NV, tB + 3 * (size_t)NV, tB + 4 * (size_t)NV,
                       acc, 1);
    // S4: dcc_p2(tA)
    hipLaunchKernelGGL(dcc_k, dim3(NB_DCC), blk, 0, stream,
                       tA, tA + NV, tA + 2 * (size_t)NV, tA + 3 * (size_t)NV, tA + 4 * (size_t)NV,
                       acc, 2);

    hipLaunchKernelGGL(finalize_k, dim3(1), dim3(1), 0, stream, acc, out);
}

// Round 13
// 375.206 us; speedup vs baseline: 1.7423x; 1.7423x over previous
//
#include <hip/hip_runtime.h>
#include <hip/hip_fp16.h>
#include <math.h>

// Volume dims (1,1,160,192,160) fp32
#define DD 160
#define HHH 192
#define WWW 160
constexpr int HW = HHH * WWW;          // 30720
constexpr int NV = DD * HHH * WWW;     // 4915200
constexpr int W4 = WWW / 4;            // 40
constexpr int HC = 4;                  // whsum H-chunk (measured best)
constexpr int DC = 4;                  // dcc D-chunk (4-wide): 160/4 = 40 chunks
constexpr int SC = 5;                  // sobel D-chunk

constexpr int NB_WH  = (W4 * DD * (HHH / HC)) / 256;   // 1200
constexpr int NB_SO  = (W4 * HHH * (DD / SC)) / 256;   // 960
constexpr int NB_LAP = (NV / 4) / 256;                 // 4800
constexpr int NB_DCC = (W4 * HHH * (DD / DC)) / 256;   // 1200

__device__ __forceinline__ float4 ldg4(const float* __restrict__ p, int idx, bool ok) {
    float4 z = make_float4(0.f, 0.f, 0.f, 0.f);
    return ok ? *(const float4*)(p + idx) : z;
}

__device__ __forceinline__ void st_h4(__half* __restrict__ t, int idx,
                                      float s0, float s1, float s2, float s3) {
    union { __half2 h2[2]; uint2 u; } pk;
    pk.h2[0] = __floats2half2_rn(s0, s1);
    pk.h2[1] = __floats2half2_rn(s2, s3);
    *(uint2*)(t + idx) = pk.u;  // idx%4==0 -> 8B aligned
}

__device__ __forceinline__ void ld_h4(const __half* __restrict__ t, int idx, float o[4]) {
    union { __half2 h2[2]; uint2 u; } pk;
    pk.u = *(const uint2*)(t + idx);
    o[0] = __low2float(pk.h2[0]); o[1] = __high2float(pk.h2[0]);
    o[2] = __low2float(pk.h2[1]); o[3] = __high2float(pk.h2[1]);
}

// ---- Laplacian body, 4 outputs/thread, fp16 out ----------------------------
__device__ __forceinline__ void lap_body(int t, const float* __restrict__ a,
                                         const float* __restrict__ b,
                                         __half* __restrict__ oa, __half* __restrict__ ob) {
    int w = (t % W4) * 4;
    int h = (t / W4) % HHH;
    int d = t / (W4 * HHH);
    int idx = (d * HHH + h) * WWW + w;
    bool dok0 = d > 0, dok1 = d < DD - 1, hok0 = h > 0, hok1 = h < HHH - 1;
#pragma unroll
    for (int s = 0; s < 2; s++) {
        const float* p = s ? b : a;
        __half* o = s ? ob : oa;
        float4 c = *(const float4*)(p + idx);
        float m1 = (w > 0) ? p[idx - 1] : 0.f;
        float p4 = (w + 4 < WWW) ? p[idx + 4] : 0.f;
        float4 dm = ldg4(p, idx - HW, dok0);
        float4 dp = ldg4(p, idx + HW, dok1);
        float4 hm = ldg4(p, idx - WWW, hok0);
        float4 hp = ldg4(p, idx + WWW, hok1);
        st_h4(o, idx,
              6.f * c.x - (m1 + c.y + dm.x + dp.x + hm.x + hp.x),
              6.f * c.y - (c.x + c.z + dm.y + dp.y + hm.y + hp.y),
              6.f * c.z - (c.y + c.w + dm.z + dp.z + hm.z + hp.z),
              6.f * c.w - (c.z + p4 + dm.w + dp.w + hm.w + hp.w));
    }
}

// ---- Sobel body, d-marching ring, 4 outputs/thread, fp16 out ---------------
__device__ __forceinline__ void sobel_slice(const float* __restrict__ p, int s, int h, int w,
                                            float a1[4], float a2[4], float a3[4]) {
#pragma unroll
    for (int k = 0; k < 4; k++) { a1[k] = 0.f; a2[k] = 0.f; a3[k] = 0.f; }
#pragma unroll
    for (int kh = -1; kh <= 1; kh++) {
        int h2 = h + kh;
        if ((unsigned)h2 < (unsigned)HHH) {
            int rb = (s * HHH + h2) * WWW + w;
            float4 cen = *(const float4*)(p + rb);
            float xm = (w > 0) ? p[rb - 1] : 0.f;
            float xp = (w + 4 < WWW) ? p[rb + 4] : 0.f;
            float xv[6] = {xm, cen.x, cen.y, cen.z, cen.w, xp};
            float smh = (kh == 0) ? 2.f : 1.f;
            float grh = (float)kh;
#pragma unroll
            for (int k = 0; k < 4; k++) {
                float gw = xv[k + 2] - xv[k];
                float pw = xv[k] + xv[k + 1] + xv[k + 2];
                float sw = pw + xv[k + 1];
                a1[k] += smh * gw;
                a2[k] += sw;
                a3[k] += grh * pw;
            }
        }
    }
}

__device__ __forceinline__ void sobel_body(int t, const float* __restrict__ a,
                                           const float* __restrict__ b,
                                           __half* __restrict__ oa, __half* __restrict__ ob) {
    int w = (t % W4) * 4;
    int h = (t / W4) % HHH;
    int c = t / (W4 * HHH);
    int d0 = c * SC;

    float A1[2][3][4], A2[2][3][4], A3[2][3][4];
#pragma unroll
    for (int r = 0; r < 2; r++)
#pragma unroll
        for (int j = 0; j < 3; j++)
#pragma unroll
            for (int k = 0; k < 4; k++) { A1[r][j][k] = 0.f; A2[r][j][k] = 0.f; A3[r][j][k] = 0.f; }

#pragma unroll
    for (int i = 0; i < SC + 2; i++) {
        int s = d0 - 1 + i;
#pragma unroll
        for (int r = 0; r < 2; r++)
#pragma unroll
            for (int k = 0; k < 4; k++) {
                A1[r][0][k] = A1[r][1][k]; A2[r][0][k] = A2[r][1][k]; A3[r][0][k] = A3[r][1][k];
                A1[r][1][k] = A1[r][2][k]; A2[r][1][k] = A2[r][2][k]; A3[r][1][k] = A3[r][2][k];
            }
        if (s >= 0 && s < DD) {
            sobel_slice(a, s, h, w, A1[0][2], A2[0][2], A3[0][2]);
            sobel_slice(b, s, h, w, A1[1][2], A2[1][2], A3[1][2]);
        } else {
#pragma unroll
            for (int r = 0; r < 2; r++)
#pragma unroll
                for (int k = 0; k < 4; k++) { A1[r][2][k] = 0.f; A2[r][2][k] = 0.f; A3[r][2][k] = 0.f; }
        }
        if (i >= 2) {
            int d = s - 1;
            int idx = (d * HHH + h) * WWW + w;
            float va[4], vb[4];
#pragma unroll
            for (int k = 0; k < 4; k++) {
                float gx = A1[0][0][k] + A1[0][1][k] + A1[0][2][k];
                float gy = A2[0][2][k] - A2[0][0][k];
                float gz = A3[0][0][k] + 2.f * A3[0][1][k] + A3[0][2][k];
                va[k] = sqrtf(gx * gx + gy * gy + gz * gz);
                gx = A1[1][0][k] + A1[1][1][k] + A1[1][2][k];
                gy = A2[1][2][k] - A2[1][0][k];
                gz = A3[1][0][k] + 2.f * A3[1][1][k] + A3[1][2][k];
                vb[k] = sqrtf(gx * gx + gy * gy + gz * gz);
            }
            st_h4(oa, idx, va[0], va[1], va[2], va[3]);
            st_h4(ob, idx, vb[0], vb[1], vb[2], vb[3]);
        }
    }
}

// ---- W+H box sums of 5 moments (R11 sequential structure, no batching) -----
__device__ __forceinline__ void q5_from(const float x[12], const float y[12], float q[5][4]) {
    float s0 = 0, s1 = 0, s2 = 0, s3 = 0, s4 = 0;
#pragma unroll
    for (int j = 0; j < 9; j++) {
        s0 += x[j]; s1 += y[j];
        s2 += x[j] * x[j]; s3 += y[j] * y[j]; s4 += x[j] * y[j];
    }
    q[0][0] = s0; q[1][0] = s1; q[2][0] = s2; q[3][0] = s3; q[4][0] = s4;
#pragma unroll
    for (int k = 1; k < 4; k++) {
        q[0][k] = q[0][k - 1] + x[k + 8] - x[k - 1];
        q[1][k] = q[1][k - 1] + y[k + 8] - y[k - 1];
        q[2][k] = q[2][k - 1] + x[k + 8] * x[k + 8] - x[k - 1] * x[k - 1];
        q[3][k] = q[3][k - 1] + y[k + 8] * y[k + 8] - y[k - 1] * y[k - 1];
        q[4][k] = q[4][k - 1] + x[k + 8] * y[k + 8] - x[k - 1] * y[k - 1];
    }
}

__device__ __forceinline__ void ld12(const float* __restrict__ p, int rowbase, int w, float x[12]) {
    bool lo = (w >= 4);
    bool hi = (w + 7 < WWW);
    float4 x0 = ldg4(p, rowbase + w - 4, lo);
    float4 x1 = *(const float4*)(p + rowbase + w);
    float4 x2 = ldg4(p, rowbase + w + 4, hi);
    x[0] = x0.x; x[1] = x0.y; x[2] = x0.z; x[3] = x0.w;
    x[4] = x1.x; x[5] = x1.y; x[6] = x1.z; x[7] = x1.w;
    x[8] = x2.x; x[9] = x2.y; x[10] = x2.z; x[11] = x2.w;
}

__device__ __forceinline__ void ld12(const __half* __restrict__ p, int rowbase, int w, float x[12]) {
    bool lo = (w >= 4);
    bool hi = (w + 7 < WWW);
    union { __half2 h2[2]; uint2 u; } u0, u1, u2;
    uint2 z = make_uint2(0, 0);
    u0.u = lo ? *(const uint2*)(p + rowbase + w - 4) : z;
    u1.u = *(const uint2*)(p + rowbase + w);
    u2.u = hi ? *(const uint2*)(p + rowbase + w + 4) : z;
    x[0] = __low2float(u0.h2[0]); x[1] = __high2float(u0.h2[0]);
    x[2] = __low2float(u0.h2[1]); x[3] = __high2float(u0.h2[1]);
    x[4] = __low2float(u1.h2[0]); x[5] = __high2float(u1.h2[0]);
    x[6] = __low2float(u1.h2[1]); x[7] = __high2float(u1.h2[1]);
    x[8] = __low2float(u2.h2[0]); x[9] = __high2float(u2.h2[0]);
    x[10] = __low2float(u2.h2[1]); x[11] = __high2float(u2.h2[1]);
}

template <typename T>
__device__ __forceinline__ void rowq5(const T* __restrict__ a, const T* __restrict__ b,
                                      int rowbase, int w, float q[5][4]) {
    float x[12], y[12];
    ld12(a, rowbase, w, x);
    ld12(b, rowbase, w, y);
    q5_from(x, y, q);
}

template <typename T>
__device__ void whsum_body(int t, const T* __restrict__ a, const T* __restrict__ b,
                           __half* __restrict__ t0, __half* __restrict__ t1,
                           __half* __restrict__ t2, __half* __restrict__ t3,
                           __half* __restrict__ t4) {
    int w = (t % W4) * 4;
    int d = (t / W4) % DD;
    int c = t / (W4 * DD);
    int h0 = c * HC;

    float S[5][4] = {{0}};
    for (int j = 0; j < 9; j++) {
        int r = h0 - 4 + j;
        if ((unsigned)r < (unsigned)HHH) {
            float q[5][4];
            rowq5(a, b, (d * HHH + r) * WWW, w, q);
#pragma unroll
            for (int qq = 0; qq < 5; qq++)
#pragma unroll
                for (int k = 0; k < 4; k++) S[qq][k] += q[qq][k];
        }
    }
    {
        int idx = (d * HHH + h0) * WWW + w;
        st_h4(t0, idx, S[0][0], S[0][1], S[0][2], S[0][3]);
        st_h4(t1, idx, S[1][0], S[1][1], S[1][2], S[1][3]);
        st_h4(t2, idx, S[2][0], S[2][1], S[2][2], S[2][3]);
        st_h4(t3, idx, S[3][0], S[3][1], S[3][2], S[3][3]);
        st_h4(t4, idx, S[4][0], S[4][1], S[4][2], S[4][3]);
    }
    for (int h = h0 + 1; h < h0 + HC; h++) {
        int rin = h + 4, rout = h - 5;
        if (rin < HHH) {
            float q[5][4];
            rowq5(a, b, (d * HHH + rin) * WWW, w, q);
#pragma unroll
            for (int qq = 0; qq < 5; qq++)
#pragma unroll
                for (int k = 0; k < 4; k++) S[qq][k] += q[qq][k];
        }
        if (rout >= 0) {
            float q[5][4];
            rowq5(a, b, (d * HHH + rout) * WWW, w, q);
#pragma unroll
            for (int qq = 0; qq < 5; qq++)
#pragma unroll
                for (int k = 0; k < 4; k++) S[qq][k] -= q[qq][k];
        }
        int idx = (d * HHH + h) * WWW + w;
        st_h4(t0, idx, S[0][0], S[0][1], S[0][2], S[0][3]);
        st_h4(t1, idx, S[1][0], S[1][1], S[1][2], S[1][3]);
        st_h4(t2, idx, S[2][0], S[2][1], S[2][2], S[2][3]);
        st_h4(t3, idx, S[3][0], S[3][1], S[3][2], S[3][3]);
        st_h4(t4, idx, S[4][0], S[4][1], S[4][2], S[4][3]);
    }
}

// ---- D box-sum + cc + reduction, 4-wide fp16 loads (R11 structure) ---------
__device__ __forceinline__ float cc1(float s0, float s1, float s2, float s3, float s4) {
    const float wsz = 729.0f;
    const float inv = 1.0f / 729.0f;
    float uI = s0 * inv;
    float uJ = s1 * inv;
    float cross = s4 - uJ * s0 - uI * s1 + uI * uJ * wsz;
    float Iv = s2 - 2.0f * uI * s0 + uI * uI * wsz;
    float Jv = s3 - 2.0f * uJ * s1 + uJ * uJ * wsz;
    return cross * cross / (Iv * Jv + 1e-5f);
}

__device__ void dcc_body(int t, const __half* __restrict__ t0, const __half* __restrict__ t1,
                         const __half* __restrict__ t2, const __half* __restrict__ t3,
                         const __half* __restrict__ t4, double* __restrict__ acc, int pair) {
    int w = (t % W4) * 4;
    int h = (t / W4) % HHH;
    int c = t / (W4 * HHH);
    int d0 = c * DC;

    float S[5][4] = {{0}};
    for (int j = 0; j < 9; j++) {
        int r = d0 - 4 + j;
        if ((unsigned)r < (unsigned)DD) {
            int idx = (r * HHH + h) * WWW + w;
            float v[5][4];
            ld_h4(t0, idx, v[0]); ld_h4(t1, idx, v[1]); ld_h4(t2, idx, v[2]);
            ld_h4(t3, idx, v[3]); ld_h4(t4, idx, v[4]);
#pragma unroll
            for (int q = 0; q < 5; q++)
#pragma unroll
                for (int k = 0; k < 4; k++) S[q][k] += v[q][k];
        }
    }
    float local = 0.f;
#pragma unroll
    for (int k = 0; k < 4; k++) local += cc1(S[0][k], S[1][k], S[2][k], S[3][k], S[4][k]);
#pragma unroll
    for (int d = 1; d < DC; d++) {
        int rin = d0 + d + 4, rout = d0 + d - 5;
        if (rin < DD) {
            int idx = (rin * HHH + h) * WWW + w;
            float v[5][4];
            ld_h4(t0, idx, v[0]); ld_h4(t1, idx, v[1]); ld_h4(t2, idx, v[2]);
            ld_h4(t3, idx, v[3]); ld_h4(t4, idx, v[4]);
#pragma unroll
            for (int q = 0; q < 5; q++)
#pragma unroll
                for (int k = 0; k < 4; k++) S[q][k] += v[q][k];
        }
        if (rout >= 0) {
            int idx = (rout * HHH + h) * WWW + w;
            float v[5][4];
            ld_h4(t0, idx, v[0]); ld_h4(t1, idx, v[1]); ld_h4(t2, idx, v[2]);
            ld_h4(t3, idx, v[3]); ld_h4(t4, idx, v[4]);
#pragma unroll
            for (int q = 0; q < 5; q++)
#pragma unroll
                for (int k = 0; k < 4; k++) S[q][k] -= v[q][k];
        }
#pragma unroll
        for (int k = 0; k < 4; k++) local += cc1(S[0][k], S[1][k], S[2][k], S[3][k], S[4][k]);
    }

    for (int off = 32; off > 0; off >>= 1) local += __shfl_down(local, off);
    __shared__ float wsum_[4];
    if ((threadIdx.x & 63) == 0) wsum_[threadIdx.x >> 6] = local;
    __syncthreads();
    if (threadIdx.x == 0) {
        float s = wsum_[0] + wsum_[1] + wsum_[2] + wsum_[3];
        atomicAdd(&acc[pair], (double)s);
    }
}

// ---- Stage kernels ----------------------------------------------------------
// S1: LJF order (whsum, sobel, lap) + zero block. (identical both schedules)
__global__ void stage1(const float* __restrict__ yt, const float* __restrict__ yp,
                       __half* __restrict__ e1a, __half* __restrict__ e1b,
                       __half* __restrict__ e2a, __half* __restrict__ e2b,
                       __half* __restrict__ ta0, __half* __restrict__ ta1,
                       __half* __restrict__ ta2, __half* __restrict__ ta3,
                       __half* __restrict__ ta4, double* __restrict__ acc) {
    int b = blockIdx.x;
    if (b < NB_WH) {
        whsum_body<float>(b * 256 + threadIdx.x, yt, yp, ta0, ta1, ta2, ta3, ta4);
    } else if (b < NB_WH + NB_SO) {
        sobel_body((b - NB_WH) * 256 + threadIdx.x, yt, yp, e2a, e2b);
    } else if (b < NB_WH + NB_SO + NB_LAP) {
        lap_body((b - NB_WH - NB_SO) * 256 + threadIdx.x, yt, yp, e1a, e1b);
    } else {
        if (threadIdx.x < 3) acc[threadIdx.x] = 0.0;
    }
}

// (fallback schedule) S2/S3: whsum first, then dcc.
__global__ void stage23(const __half* __restrict__ ea, const __half* __restrict__ eb,
                        __half* __restrict__ o0, __half* __restrict__ o1,
                        __half* __restrict__ o2, __half* __restrict__ o3,
                        __half* __restrict__ o4,
                        const __half* __restrict__ i0, const __half* __restrict__ i1,
                        const __half* __restrict__ i2, const __half* __restrict__ i3,
                        const __half* __restrict__ i4, double* __restrict__ acc, int pair) {
    int b = blockIdx.x;
    if (b < NB_WH) {
        whsum_body<__half>(b * 256 + threadIdx.x, ea, eb, o0, o1, o2, o3, o4);
    } else {
        dcc_body((b - NB_WH) * 256 + threadIdx.x, i0, i1, i2, i3, i4, acc, pair);
    }
}

__global__ void dcc_k(const __half* __restrict__ t0, const __half* __restrict__ t1,
                      const __half* __restrict__ t2, const __half* __restrict__ t3,
                      const __half* __restrict__ t4, double* __restrict__ acc, int pair) {
    dcc_body(blockIdx.x * 256 + threadIdx.x, t0, t1, t2, t3, t4, acc, pair);
}

// (wide schedule) S2b: whsum_p1(e1->tB) + whsum_p2(e2->tC) + dcc_p0(tA->acc0)
__global__ void stage2b(const __half* __restrict__ e1a, const __half* __restrict__ e1b,
                        const __half* __restrict__ e2a, const __half* __restrict__ e2b,
                        __half* __restrict__ tB, __half* __restrict__ tC,
                        const __half* __restrict__ tA, double* __restrict__ acc) {
    int b = blockIdx.x;
    size_t nv = (size_t)NV;
    if (b < NB_WH) {
        whsum_body<__half>(b * 256 + threadIdx.x, e1a, e1b,
                           tB, tB + nv, tB + 2 * nv, tB + 3 * nv, tB + 4 * nv);
    } else if (b < 2 * NB_WH) {
        whsum_body<__half>((b - NB_WH) * 256 + threadIdx.x, e2a, e2b,
                           tC, tC + nv, tC + 2 * nv, tC + 3 * nv, tC + 4 * nv);
    } else {
        dcc_body((b - 2 * NB_WH) * 256 + threadIdx.x,
                 tA, tA + nv, tA + 2 * nv, tA + 3 * nv, tA + 4 * nv, acc, 0);
    }
}

// (wide schedule) S3b: dcc_p1(tB->acc1) + dcc_p2(tC->acc2)
__global__ void stage3b(const __half* __restrict__ tB, const __half* __restrict__ tC,
                        double* __restrict__ acc) {
    int b = blockIdx.x;
    size_t nv = (size_t)NV;
    if (b < NB_DCC) {
        dcc_body(b * 256 + threadIdx.x,
                 tB, tB + nv, tB + 2 * nv, tB + 3 * nv, tB + 4 * nv, acc, 1);
    } else {
        dcc_body((b - NB_DCC) * 256 + threadIdx.x,
                 tC, tC + nv, tC + 2 * nv, tC + 3 * nv, tC + 4 * nv, acc, 2);
    }
}

__global__ void finalize_k(const double* __restrict__ acc, float* __restrict__ out) {
    if (threadIdx.x == 0) {
        double v = 0.8 * acc[0] + 0.1 * acc[1] + 0.1 * acc[2];
        out[0] = (float)(-v / (double)NV);
    }
}

extern "C" void kernel_launch(void* const* d_in, const int* in_sizes, int n_in,
                              void* d_out, int out_size, void* d_ws, size_t ws_size,
                              hipStream_t stream) {
    const float* yt = (const float*)d_in[0];
    const float* yp = (const float*)d_in[1];
    float* out = (float*)d_out;

    // ws layout: acc(256B) | e1a e1b e2a e2b | tA(5) | tB(5) [| tC(5) if room]
    double* acc = (double*)d_ws;
    __half* base = (__half*)((char*)d_ws + 256);
    size_t nv = (size_t)NV;
    __half* e1a = base + 0 * nv;
    __half* e1b = base + 1 * nv;
    __half* e2a = base + 2 * nv;
    __half* e2b = base + 3 * nv;
    __half* tA = base + 4 * nv;   // 5 vols
    __half* tB = base + 9 * nv;   // 5 vols
    __half* tC = base + 14 * nv;  // 5 vols (wide schedule only)

    bool wide = ws_size >= 256 + 19 * nv * sizeof(__half);

    dim3 blk(256);

    // S1: whsum_p0 + sobel + lap + zero (LJF order)
    hipLaunchKernelGGL(stage1, dim3(NB_WH + NB_SO + NB_LAP + 1), blk, 0, stream,
                       yt, yp, e1a, e1b, e2a, e2b,
                       tA, tA + nv, tA + 2 * nv, tA + 3 * nv, tA + 4 * nv, acc);

    if (wide) {
        // S2b: whsum_p1 + whsum_p2 + dcc_p0
        hipLaunchKernelGGL(stage2b, dim3(2 * NB_WH + NB_DCC), blk, 0, stream,
                           e1a, e1b, e2a, e2b, tB, tC, tA, acc);
        // S3b: dcc_p1 + dcc_p2
        hipLaunchKernelGGL(stage3b, dim3(2 * NB_DCC), blk, 0, stream, tB, tC, acc);
    } else {
        // Fallback: R11 schedule
        hipLaunchKernelGGL(stage23, dim3(NB_WH + NB_DCC), blk, 0, stream,
                           e1a, e1b,
                           tB, tB + nv, tB + 2 * nv, tB + 3 * nv, tB + 4 * nv,
                           tA, tA + nv, tA + 2 * nv, tA + 3 * nv, tA + 4 * nv,
                           acc, 0);
        hipLaunchKernelGGL(stage23, dim3(NB_WH + NB_DCC), blk, 0, stream,
                           e2a, e2b,
                           tA, tA + nv, tA + 2 * nv, tA + 3 * nv, tA + 4 * nv,
                           tB, tB + nv, tB + 2 * nv, tB + 3 * nv, tB + 4 * nv,
                           acc, 1);
        hipLaunchKernelGGL(dcc_k, dim3(NB_DCC), blk, 0, stream,
                           tA, tA + nv, tA + 2 * nv, tA + 3 * nv, tA + 4 * nv, acc, 2);
    }

    hipLaunchKernelGGL(finalize_k, dim3(1), dim3(1), 0, stream, acc, out);
}